// Round 1
// 314.481 us; speedup vs baseline: 1.0712x; 1.0712x over previous
//
#include <hip/hip_runtime.h>
#include <hip/hip_bf16.h>

// Encoder_multi: zero-state single-step bidirectional 2-layer LSTM.
// h0=c0=0 => no recurrence, W_hh unused, forget gate dead.
//   gates = inp @ W_ih^T + (b_ih+b_hh); c = sig(i)*tanh(g); h = sig(o)*tanh(c)
// Two GEMMs: (8192 x 3072 x 512) and (8192 x 3072 x 1024).
//
// Round-3 changes vs round-2 (336.9 us):
//  * W packing is now GATE-INTERLEAVED: packed row n = h*6 + gi,
//    gi in {0:i_f,1:g_f,2:o_f,3:i_b,4:g_b,5:o_b}. A BN=96 column tile
//    (16 h x 6 gates) owns complete sextets -> activation epilogue fused
//    into the GEMM via an LDS f32 round-trip. The 50MB gates write + 50MB
//    epilogue re-read + 2 epilogue dispatches per layer are eliminated.
//  * staging: back to __builtin_amdgcn_global_load_lds width=16 (m97 path,
//    874 vs 646 TF over reg-staging at this exact structure). LDS layout is
//    strictly linear (byte = chunk*16, chunk = tid-linear) which is exactly
//    the wave-uniform-base + lane*16 pattern the instruction writes.
//
// ws layout (bytes), all 16B-aligned:
//   flag  @ 0
//   bc0   @ 1024        12,288  (3072 f32 combined bias, gate-interleaved)
//   bc1   @ 16384       12,288
//   Wp0   @ 32768       3,145,728   (3072x512  bf16, B^T rows gate-interleaved)
//   Wp1   @ 4194304     6,291,456   (3072x1024 bf16)
//   e0    @ 10485760    8,388,608   (8192x512 bf16 gathered embeddings)
//   inp1  @ 18874368    16,777,216  (8192x1024 bf16)
//   total ~36 MB

using bf16x8 = __attribute__((ext_vector_type(8))) short;
using f32x4  = __attribute__((ext_vector_type(4))) float;

__device__ __forceinline__ float sigf(float x) { return 1.0f / (1.0f + expf(-x)); }
__device__ __forceinline__ unsigned short f2bf(float f)
{
    __hip_bfloat16 h = __float2bfloat16(f);
    return *(unsigned short*)&h;
}

__device__ __forceinline__ void gload16(const void* g, void* l)
{
    __builtin_amdgcn_global_load_lds(
        (const __attribute__((address_space(1))) unsigned int*)g,
        (__attribute__((address_space(3))) unsigned int*)l, 16, 0, 0);
}

// ---- dtype detector: are the float tensors bf16 (flag=1) or f32 (flag=0)? ----
__global__ void detect(const unsigned int* __restrict__ emb, int* __restrict__ flag)
{
    int ok = 0;
    for (int i = threadIdx.x; i < 256; i += 64) {
        unsigned lo = emb[i] & 0xFFFFu;
        int e = (lo >> 7) & 0xFF;
        if ((e >= 96 && e < 160) || lo == 0) ok++;
    }
#pragma unroll
    for (int off = 32; off; off >>= 1) ok += __shfl_down(ok, off);
    if (threadIdx.x == 0) *flag = (ok >= 192) ? 1 : 0;
}

// ---- gather embeddings into canonical bf16 e0 (8192 x 512) ----
__global__ void gather_convert(const int* __restrict__ x, const void* __restrict__ emb,
                               uint4* __restrict__ e0, const int* __restrict__ flag)
{
    int idx = blockIdx.x * 256 + threadIdx.x;   // one 8-elem chunk each; 8192*64 total
    int m = idx >> 6, r = idx & 63;
    long srow = x[m];
    uint4 v;
    if (*flag) {
        v = ((const uint4*)emb)[srow * 64 + r];
    } else {
        const float4* ef = (const float4*)emb;
        float4 a = ef[srow * 128 + r * 2], b = ef[srow * 128 + r * 2 + 1];
        unsigned short h[8] = { f2bf(a.x), f2bf(a.y), f2bf(a.z), f2bf(a.w),
                                f2bf(b.x), f2bf(b.y), f2bf(b.z), f2bf(b.w) };
        v = *(uint4*)h;
    }
    e0[idx] = v;
}

// ---- pack W_ih rows gate-interleaved into B^T (3072 x K) canonical bf16 ----
// packed row n = h*6 + gi; gi: 0=i_f 1=g_f 2=o_f 3=i_b 4=g_b 5=o_b
__global__ void pack_w(const void* __restrict__ src, uint4* __restrict__ dst,
                       int k8shift, const int* __restrict__ flag)
{
    int idx = blockIdx.x * 256 + threadIdx.x;   // one 8-elem chunk per thread
    int n = idx >> k8shift;                     // packed row 0..3071
    int r = idx & ((1 << k8shift) - 1);
    int h = n / 6, gi = n % 6;
    int dir = (gi >= 3) ? 1 : 0;
    int gate = gi - dir * 3;                    // 0:i 1:g 2:o
    int sg = (gate == 0) ? 0 : (gate + 1);      // source gate block {0,2,3} of {i,f,g,o}
    long srcrow = dir * 2048 + sg * 512 + h;
    long c8 = (srcrow << k8shift) + r;          // 8-element chunk index in source
    if (*flag) {
        dst[idx] = ((const uint4*)src)[c8];
    } else {
        const float4* sf = (const float4*)src;
        float4 a = sf[c8 * 2], b = sf[c8 * 2 + 1];
        unsigned short h8[8] = { f2bf(a.x), f2bf(a.y), f2bf(a.z), f2bf(a.w),
                                 f2bf(b.x), f2bf(b.y), f2bf(b.z), f2bf(b.w) };
        dst[idx] = *(uint4*)h8;
    }
}

__global__ void pack_bias(const void* __restrict__ bi, const void* __restrict__ bh,
                          float* __restrict__ bc, const int* __restrict__ flag)
{
    int n = blockIdx.x * 256 + threadIdx.x;     // 0..3071 (gate-interleaved)
    int h = n / 6, gi = n % 6;
    int dir = (gi >= 3) ? 1 : 0;
    int gate = gi - dir * 3;
    int sg = (gate == 0) ? 0 : (gate + 1);
    int s = dir * 2048 + sg * 512 + h;
    float vi, vh;
    if (*flag) {
        vi = __bfloat162float(((const __hip_bfloat16*)bi)[s]);
        vh = __bfloat162float(((const __hip_bfloat16*)bh)[s]);
    } else {
        vi = ((const float*)bi)[s];
        vh = ((const float*)bh)[s];
    }
    bc[n] = vi + vh;
}

// ---- fused GEMM + activation epilogue ----
// C(M x 3072) = A(M x K) * Bp(3072 x K)^T, bf16 in, f32 acc.
// Tile 128x96 (= 16 h x 6 gates), BK=32, 256 thr = 4 waves, wave = 64x48
// (4x3 of 16x16x32 MFMA). Staging: global_load_lds width=16, linear LDS.
// Epilogue: acc -> LDS (two 64-row passes, stride 97) -> bias+act -> outputs.
// d_out flat: h_last(2,32,512) @0 | c_last(2,32,512) @32768 | enc(B,T,2,H) @65536
template <int LAYER>
__global__ __launch_bounds__(256)
void gemm_fused(const unsigned short* __restrict__ A,
                const unsigned short* __restrict__ Bp,
                const float* __restrict__ bc,
                unsigned short* __restrict__ inp1,
                void* __restrict__ outv,
                const int* __restrict__ flag,
                int K)
{
    constexpr int BM = 128, BN = 96, BK = 32;
    __shared__ __align__(16) char smem[64 * 97 * 4];        // 24,832 B
    unsigned short* As = (unsigned short*)smem;             // [128][32] = 8 KB
    unsigned short* Bs = (unsigned short*)(smem + 8192);    // [96][32]  = 6 KB
    float* Cs = (float*)smem;                               // [64][97] epilogue

    const int tid = threadIdx.x;
    const int bm = blockIdx.x;
    const int bn = blockIdx.y;
    const int K8 = K >> 3;

    const uint4* a4 = (const uint4*)A;
    const uint4* b4 = (const uint4*)Bp;
    uint4* As4 = (uint4*)As;
    uint4* Bs4 = (uint4*)Bs;

    // A tile: 512 16B chunks, thread owns tid and tid+256. chunk ci -> row ci>>2,
    // k-off (ci&3)*8. LDS byte = ci*16 (tid-linear => gload_lds-compatible).
    // B tile: 384 chunks; thread owns tid, and tid+256 if tid<128 (wave-uniform).
    const int ciA1 = tid + 256;
    const int ciB1 = tid + 256;
    const long aOff0 = (long)(bm * BM + (tid  >> 2)) * K8 + (tid  & 3);
    const long aOff1 = (long)(bm * BM + (ciA1 >> 2)) * K8 + (ciA1 & 3);
    const long bOff0 = (long)(bn * BN + (tid  >> 2)) * K8 + (tid  & 3);
    const long bOff1 = (long)(bn * BN + (ciB1 >> 2)) * K8 + (ciB1 & 3);

    const int wave = tid >> 6, lane = tid & 63;
    const int wr = (wave >> 1) << 6;            // wave row offset: 0 / 64
    const int wc = (wave & 1) * 48;             // wave col offset: 0 / 48
    const int lr = lane & 15, q = lane >> 4;

    f32x4 acc[4][3] = {};

    for (int k0 = 0; k0 < K; k0 += BK) {
        const int k8 = k0 >> 3;
        __syncthreads();                        // previous iter's LDS reads done
        gload16(a4 + aOff0 + k8, As4 + tid);
        gload16(a4 + aOff1 + k8, As4 + ciA1);
        gload16(b4 + bOff0 + k8, Bs4 + tid);
        if (tid < 128) gload16(b4 + bOff1 + k8, Bs4 + ciB1);
        __syncthreads();                        // vmcnt(0) drain -> staging visible

        bf16x8 af[4], bf[3];
#pragma unroll
        for (int i = 0; i < 4; ++i)
            af[i] = *(const bf16x8*)&As[(wr + i * 16 + lr) * BK + q * 8];
#pragma unroll
        for (int j = 0; j < 3; ++j)
            bf[j] = *(const bf16x8*)&Bs[(wc + j * 16 + lr) * BK + q * 8];
#pragma unroll
        for (int i = 0; i < 4; ++i)
#pragma unroll
            for (int j = 0; j < 3; ++j)
                acc[i][j] = __builtin_amdgcn_mfma_f32_16x16x32_bf16(af[i], bf[j], acc[i][j], 0, 0, 0);
    }

    // ---- fused epilogue ----
    const bool isbf = (*flag != 0);             // uniform branch
    auto store = [&](long i, float v) {
        if (isbf) ((__hip_bfloat16*)outv)[i] = __float2bfloat16(v);
        else      ((float*)outv)[i] = v;
    };

    const int hl = tid & 15;                    // fixed h-slot per thread
    float bcv[6];
#pragma unroll
    for (int gi = 0; gi < 6; ++gi) bcv[gi] = bc[bn * BN + hl * 6 + gi];

#pragma unroll
    for (int pass = 0; pass < 2; ++pass) {
        __syncthreads();                        // Cs free (staging / prev pass done)
        if ((wr >> 6) == pass) {
            // D layout: col = lane&15, row = (lane>>4)*4 + reg (m89/m91-verified)
#pragma unroll
            for (int i = 0; i < 4; ++i)
#pragma unroll
                for (int j = 0; j < 3; ++j)
#pragma unroll
                    for (int r = 0; r < 4; ++r)
                        Cs[(i * 16 + q * 4 + r) * 97 + wc + j * 16 + lr] = acc[i][j][r];
        }
        __syncthreads();
#pragma unroll
        for (int t = 0; t < 4; ++t) {
            int ml = (tid >> 4) + t * 16;       // 0..63 local row
            float z[6];
#pragma unroll
            for (int gi = 0; gi < 6; ++gi) z[gi] = Cs[ml * 97 + hl * 6 + gi] + bcv[gi];
            float c0 = sigf(z[0]) * tanhf(z[1]);        // forward dir
            float h0 = sigf(z[2]) * tanhf(c0);
            float c1 = sigf(z[3]) * tanhf(z[4]);        // backward dir
            float h1 = sigf(z[5]) * tanhf(c1);

            long m = (long)bm * BM + pass * 64 + ml;
            int hg = bn * 16 + hl;

            if constexpr (LAYER == 0) {
                inp1[m * 1024 + hg]       = f2bf(h0);
                inp1[m * 1024 + 512 + hg] = f2bf(h1);
            }
            store(65536 + m * 1024 + LAYER * 512 + hg, h0 + h1);    // encoder_out
            if ((m & 255) == 255) {             // t == T-1
                int b = (int)(m >> 8);
                store(LAYER * 16384 + b * 512 + hg, h0);            // h_last (fwd)
                store(32768 + LAYER * 16384 + b * 512 + hg, c0);    // c_last (fwd)
            }
        }
    }
}

extern "C" void kernel_launch(void* const* d_in, const int* in_sizes, int n_in,
                              void* d_out, int out_size, void* d_ws, size_t ws_size,
                              hipStream_t stream)
{
    const int* x      = (const int*)d_in[0];
    const void* emb   = d_in[1];
    const void* Wih0  = d_in[2];
    const void* bih0  = d_in[4];
    const void* bhh0  = d_in[5];
    const void* Wih1  = d_in[6];
    const void* bih1  = d_in[8];
    const void* bhh1  = d_in[9];

    char* ws = (char*)d_ws;
    int*   flag           = (int*)(ws);
    float* bc0            = (float*)(ws + 1024);
    float* bc1            = (float*)(ws + 16384);
    unsigned short* Wp0   = (unsigned short*)(ws + 32768);
    unsigned short* Wp1   = (unsigned short*)(ws + 4194304);
    unsigned short* e0    = (unsigned short*)(ws + 10485760);
    unsigned short* inp1  = (unsigned short*)(ws + 18874368);

    detect<<<1, 64, 0, stream>>>((const unsigned int*)emb, flag);
    gather_convert<<<2048, 256, 0, stream>>>(x, emb, (uint4*)e0, flag);
    pack_w<<<768, 256, 0, stream>>>(Wih0, (uint4*)Wp0, 6, flag);    // K=512
    pack_w<<<1536, 256, 0, stream>>>(Wih1, (uint4*)Wp1, 7, flag);   // K=1024
    pack_bias<<<12, 256, 0, stream>>>(bih0, bhh0, bc0, flag);
    pack_bias<<<12, 256, 0, stream>>>(bih1, bhh1, bc1, flag);

    gemm_fused<0><<<dim3(64, 32), 256, 0, stream>>>(e0, Wp0, bc0, inp1, d_out, flag, 512);
    gemm_fused<1><<<dim3(64, 32), 256, 0, stream>>>(inp1, Wp1, bc1, nullptr, d_out, flag, 1024);
}

// Round 2
// 298.116 us; speedup vs baseline: 1.1300x; 1.0549x over previous
//
#include <hip/hip_runtime.h>
#include <hip/hip_bf16.h>

// Encoder_multi: zero-state single-step bidirectional 2-layer LSTM.
// h0=c0=0 => no recurrence, W_hh unused, forget gate dead.
//   gates = inp @ W_ih^T + (b_ih+b_hh); c = sig(i)*tanh(g); h = sig(o)*tanh(c)
// Two GEMMs: (8192 x 3072 x 512) and (8192 x 3072 x 1024).
//
// Round-4 changes vs round-3 (314.5 us; gemm 88 us, MfmaUtil 24.6%):
//  * GEMM: 2-phase double-buffered pipeline (T3-minimum). Stage(t+1) issued
//    BEFORE ds_read+MFMA of tile t; ONE __syncthreads (vmcnt(0) drain) per
//    K-step, overlapped by the MFMA phase instead of draining right after
//    issue. BM 128->256 (512 thr, 8 waves): intensity +27%, LDS 44KB,
//    3 blocks/CU = 24 waves.
//  * All 6 prep kernels merged into ONE `prep` dispatch; each block
//    re-derives the dtype flag locally from emb[0:256] words (L2-cached).
//    Dispatch count 8 -> 3 (kills ~5 launch gaps).
//  * Epilogue activations via __expf (error ~1e-6 << bf16 rounding).
//
// ws layout (bytes), all 16B-aligned:
//   flag  @ 0
//   bc0   @ 1024        12,288  (3072 f32 combined bias, gate-interleaved)
//   bc1   @ 16384       12,288
//   Wp0   @ 32768       3,145,728   (3072x512  bf16, B^T rows gate-interleaved)
//   Wp1   @ 4194304     6,291,456   (3072x1024 bf16)
//   e0    @ 10485760    8,388,608   (8192x512 bf16 gathered embeddings)
//   inp1  @ 18874368    16,777,216  (8192x1024 bf16)

using bf16x8 = __attribute__((ext_vector_type(8))) short;
using f32x4  = __attribute__((ext_vector_type(4))) float;

__device__ __forceinline__ unsigned short f2bf(float f)
{
    __hip_bfloat16 h = __float2bfloat16(f);
    return *(unsigned short*)&h;
}
__device__ __forceinline__ float sigf(float x)  { return 1.0f / (1.0f + __expf(-x)); }
__device__ __forceinline__ float tanhfast(float x)
{
    // 1 - 2/(e^{2x}+1); exact limits at +-inf, ~1e-6 rel error
    return 1.0f - 2.0f / (__expf(2.0f * x) + 1.0f);
}

__device__ __forceinline__ void gload16(const void* g, void* l)
{
    __builtin_amdgcn_global_load_lds(
        (const __attribute__((address_space(1))) unsigned int*)g,
        (__attribute__((address_space(3))) unsigned int*)l, 16, 0, 0);
}

// ---- single prep dispatch: local dtype detect + gather + pack W + bias ----
// blocks: [0,2048) gather e0 | [2048,2816) pack Wp0 | [2816,4352) pack Wp1
//         [4352,4376) bias (12 blocks bc0, 12 blocks bc1); block 4352 writes flag
__global__ __launch_bounds__(256)
void prep(const int* __restrict__ x, const void* __restrict__ emb,
          const void* __restrict__ Wih0, const void* __restrict__ Wih1,
          const void* __restrict__ bih0, const void* __restrict__ bhh0,
          const void* __restrict__ bih1, const void* __restrict__ bhh1,
          uint4* __restrict__ e0, uint4* __restrict__ Wp0, uint4* __restrict__ Wp1,
          float* __restrict__ bc0, float* __restrict__ bc1, int* __restrict__ flag)
{
    // local dtype detect over emb[0:256] u32 words (bf16 -> low half is a real
    // value: exponent sane or zero; f32 -> low half is mantissa junk, ~25% pass)
    __shared__ int oks[4];
    {
        unsigned lo = ((const unsigned int*)emb)[threadIdx.x] & 0xFFFFu;
        int e = (lo >> 7) & 0xFF;
        int ok = ((e >= 96 && e < 160) || lo == 0) ? 1 : 0;
#pragma unroll
        for (int off = 32; off; off >>= 1) ok += __shfl_down(ok, off);
        if ((threadIdx.x & 63) == 0) oks[threadIdx.x >> 6] = ok;
    }
    __syncthreads();
    const bool isbf = (oks[0] + oks[1] + oks[2] + oks[3]) >= 192;
    const int bid = blockIdx.x, tid = threadIdx.x;

    if (bid < 2048) {                                   // ---- gather e0 ----
        int idx = bid * 256 + tid;                      // 8-elem chunk
        int m = idx >> 6, r = idx & 63;
        long srow = x[m];
        uint4 v;
        if (isbf) {
            v = ((const uint4*)emb)[srow * 64 + r];
        } else {
            const float4* ef = (const float4*)emb;
            float4 a = ef[srow * 128 + r * 2], b = ef[srow * 128 + r * 2 + 1];
            unsigned short h[8] = { f2bf(a.x), f2bf(a.y), f2bf(a.z), f2bf(a.w),
                                    f2bf(b.x), f2bf(b.y), f2bf(b.z), f2bf(b.w) };
            v = *(uint4*)h;
        }
        e0[idx] = v;
    } else if (bid < 4352) {                            // ---- pack W ----
        const bool L0 = bid < 2816;
        const int  ks = L0 ? 6 : 7;                     // chunks/row = K/8
        int idx = (L0 ? (bid - 2048) : (bid - 2816)) * 256 + tid;
        const void* src = L0 ? Wih0 : Wih1;
        uint4* dst = L0 ? Wp0 : Wp1;
        int n = idx >> ks, r = idx & ((1 << ks) - 1);   // packed row, chunk in row
        int h = n / 6, gi = n % 6;                      // gate-interleaved
        int dir = (gi >= 3) ? 1 : 0;
        int gate = gi - dir * 3;                        // 0:i 1:g 2:o
        int sg = (gate == 0) ? 0 : (gate + 1);          // {0,2,3} of {i,f,g,o}
        long c8 = ((long)(dir * 2048 + sg * 512 + h) << ks) + r;
        if (isbf) {
            dst[idx] = ((const uint4*)src)[c8];
        } else {
            const float4* sf = (const float4*)src;
            float4 a = sf[c8 * 2], b = sf[c8 * 2 + 1];
            unsigned short h8[8] = { f2bf(a.x), f2bf(a.y), f2bf(a.z), f2bf(a.w),
                                     f2bf(b.x), f2bf(b.y), f2bf(b.z), f2bf(b.w) };
            dst[idx] = *(uint4*)h8;
        }
    } else {                                            // ---- bias ----
        int b2 = bid - 4352;
        if (b2 == 0 && tid == 0) *flag = isbf ? 1 : 0;  // publish for GEMM epilogue
        const bool L0 = b2 < 12;
        int n = (L0 ? b2 : (b2 - 12)) * 256 + tid;      // 0..3071 gate-interleaved
        int h = n / 6, gi = n % 6;
        int dir = (gi >= 3) ? 1 : 0;
        int gate = gi - dir * 3;
        int sg = (gate == 0) ? 0 : (gate + 1);
        int s = dir * 2048 + sg * 512 + h;
        const void* bi = L0 ? bih0 : bih1;
        const void* bh = L0 ? bhh0 : bhh1;
        float* bc = L0 ? bc0 : bc1;
        float vi, vh;
        if (isbf) {
            vi = __bfloat162float(((const __hip_bfloat16*)bi)[s]);
            vh = __bfloat162float(((const __hip_bfloat16*)bh)[s]);
        } else {
            vi = ((const float*)bi)[s];
            vh = ((const float*)bh)[s];
        }
        bc[n] = vi + vh;
    }
}

// ---- fused GEMM + activation epilogue, 2-phase double-buffered pipeline ----
// C(M x 3072) = A(M x K) * Bp(3072 x K)^T, bf16 in, f32 acc.
// Tile 256x96 (16 h x 6 gates), BK=32, 512 thr = 8 waves (4 row-pairs x 2 col),
// wave = 64x48 = 4x3 of 16x16x32 MFMA.
// LDS: A dbuf 2x16K @0, B dbuf 2x6K @32768 (44KB, 3 blocks/CU = 24 waves/CU).
// Loop: stage(t+1) FIRST, then ds_read+MFMA(t), then ONE __syncthreads whose
// vmcnt(0) drain is overlapped by the MFMA phase (T3-minimum pipeline).
// Epilogue: Cs[64][97] f32 overlays the A buffers; 4 passes of 64 rows.
// d_out flat: h_last(2,32,512) @0 | c_last(2,32,512) @32768 | enc(B,T,2,H) @65536
template <int LAYER>
__global__ __launch_bounds__(512)
void gemm_fused(const unsigned short* __restrict__ A,
                const unsigned short* __restrict__ Bp,
                const float* __restrict__ bc,
                unsigned short* __restrict__ inp1,
                void* __restrict__ outv,
                const int* __restrict__ flag,
                int K)
{
    constexpr int BM = 256, BN = 96, BK = 32;
    __shared__ __align__(16) char smem[45056];

    const int tid = threadIdx.x, bm = blockIdx.x, bn = blockIdx.y;
    const int K8 = K >> 3;
    const uint4* a4 = (const uint4*)A;
    const uint4* b4 = (const uint4*)Bp;

    // A tile: 1024 chunks (row = ci>>2, kq = ci&3); thread owns ci=tid, tid+512.
    // B tile: 384 chunks; threads 0..383 (waves 0-5, wave-uniform predicate).
    const long aBase0 = (long)(bm * BM + (tid >> 2)) * K8 + (tid & 3);
    const long aBase1 = aBase0 + (long)128 * K8;
    const long bBase0 = (long)(bn * BN + (tid >> 2)) * K8 + (tid & 3);
    const bool bact = tid < 384;

    const int wave = tid >> 6, lane = tid & 63;
    const int wr = (wave >> 1) * 64;            // 0/64/128/192
    const int wc = (wave & 1) * 48;             // 0/48
    const int lr = lane & 15, q = lane >> 4;

    f32x4 acc[4][3] = {};
    const int NT = K / BK;

    auto stage = [&](int buf, int k8) {
        uint4* As4 = (uint4*)(smem + buf * 16384);
        uint4* Bs4 = (uint4*)(smem + 32768 + buf * 6144);
        gload16(a4 + aBase0 + k8, As4 + tid);
        gload16(a4 + aBase1 + k8, As4 + tid + 512);
        if (bact) gload16(b4 + bBase0 + k8, Bs4 + tid);
    };

    stage(0, 0);
    __syncthreads();                            // buf0 ready
    for (int t = 0; t < NT; ++t) {
        if (t + 1 < NT) stage((t + 1) & 1, (t + 1) * (BK >> 3));
        const unsigned short* As = (const unsigned short*)(smem + (t & 1) * 16384);
        const unsigned short* Bs = (const unsigned short*)(smem + 32768 + (t & 1) * 6144);
        bf16x8 af[4], bf[3];
#pragma unroll
        for (int i = 0; i < 4; ++i)
            af[i] = *(const bf16x8*)&As[(wr + i * 16 + lr) * BK + q * 8];
#pragma unroll
        for (int j = 0; j < 3; ++j)
            bf[j] = *(const bf16x8*)&Bs[(wc + j * 16 + lr) * BK + q * 8];
#pragma unroll
        for (int i = 0; i < 4; ++i)
#pragma unroll
            for (int j = 0; j < 3; ++j)
                acc[i][j] = __builtin_amdgcn_mfma_f32_16x16x32_bf16(af[i], bf[j], acc[i][j], 0, 0, 0);
        __syncthreads();                        // drains this iter's stage (vmcnt 0)
    }

    // ---- fused epilogue: Cs overlays A buffers ----
    float* Cs = (float*)smem;                   // [64][97]
    const bool isbf = (*flag != 0);             // uniform branch
    auto store = [&](long i, float v) {
        if (isbf) ((__hip_bfloat16*)outv)[i] = __float2bfloat16(v);
        else      ((float*)outv)[i] = v;
    };

    const int hl = tid & 15;                    // fixed h-slot per thread
    float bcv[6];
#pragma unroll
    for (int gi = 0; gi < 6; ++gi) bcv[gi] = bc[bn * BN + hl * 6 + gi];

    for (int p = 0; p < 4; ++p) {               // 64 rows per pass
        if ((wave >> 1) == p) {
            // D layout: col = lane&15, row = (lane>>4)*4 + reg (m89/m91-verified)
#pragma unroll
            for (int i = 0; i < 4; ++i)
#pragma unroll
                for (int j = 0; j < 3; ++j)
#pragma unroll
                    for (int r = 0; r < 4; ++r)
                        Cs[(i * 16 + q * 4 + r) * 97 + wc + j * 16 + lr] = acc[i][j][r];
        }
        __syncthreads();
#pragma unroll
        for (int t2 = 0; t2 < 2; ++t2) {
            int ml = (tid >> 4) + t2 * 32;      // 0..63 local row
            float z[6];
#pragma unroll
            for (int gi = 0; gi < 6; ++gi) z[gi] = Cs[ml * 97 + hl * 6 + gi] + bcv[gi];
            float c0 = sigf(z[0]) * tanhfast(z[1]);     // forward dir
            float h0 = sigf(z[2]) * tanhfast(c0);
            float c1 = sigf(z[3]) * tanhfast(z[4]);     // backward dir
            float h1 = sigf(z[5]) * tanhfast(c1);

            long m = (long)bm * BM + p * 64 + ml;
            int hg = bn * 16 + hl;

            if constexpr (LAYER == 0) {
                inp1[m * 1024 + hg]       = f2bf(h0);
                inp1[m * 1024 + 512 + hg] = f2bf(h1);
            }
            store(65536 + m * 1024 + LAYER * 512 + hg, h0 + h1);    // encoder_out
            if ((m & 255) == 255) {             // t == T-1
                int b = (int)(m >> 8);
                store(LAYER * 16384 + b * 512 + hg, h0);            // h_last (fwd)
                store(32768 + LAYER * 16384 + b * 512 + hg, c0);    // c_last (fwd)
            }
        }
        if (p < 3) __syncthreads();             // Cs reads done before next pass
    }
}

extern "C" void kernel_launch(void* const* d_in, const int* in_sizes, int n_in,
                              void* d_out, int out_size, void* d_ws, size_t ws_size,
                              hipStream_t stream)
{
    const int* x      = (const int*)d_in[0];
    const void* emb   = d_in[1];
    const void* Wih0  = d_in[2];
    const void* bih0  = d_in[4];
    const void* bhh0  = d_in[5];
    const void* Wih1  = d_in[6];
    const void* bih1  = d_in[8];
    const void* bhh1  = d_in[9];

    char* ws = (char*)d_ws;
    int*   flag           = (int*)(ws);
    float* bc0            = (float*)(ws + 1024);
    float* bc1            = (float*)(ws + 16384);
    unsigned short* Wp0   = (unsigned short*)(ws + 32768);
    unsigned short* Wp1   = (unsigned short*)(ws + 4194304);
    unsigned short* e0    = (unsigned short*)(ws + 10485760);
    unsigned short* inp1  = (unsigned short*)(ws + 18874368);

    prep<<<4376, 256, 0, stream>>>(x, emb, Wih0, Wih1, bih0, bhh0, bih1, bhh1,
                                   (uint4*)e0, (uint4*)Wp0, (uint4*)Wp1, bc0, bc1, flag);

    gemm_fused<0><<<dim3(32, 32), 512, 0, stream>>>(e0, Wp0, bc0, inp1, d_out, flag, 512);
    gemm_fused<1><<<dim3(32, 32), 512, 0, stream>>>(inp1, Wp1, bc1, nullptr, d_out, flag, 1024);
}

// Round 3
// 295.065 us; speedup vs baseline: 1.1417x; 1.0103x over previous
//
#include <hip/hip_runtime.h>
#include <hip/hip_bf16.h>

// Encoder_multi: zero-state single-step bidirectional 2-layer LSTM.
// h0=c0=0 => no recurrence, W_hh unused, forget gate dead.
//   gates = inp @ W_ih^T + (b_ih+b_hh); c = sig(i)*tanh(g); h = sig(o)*tanh(c)
// Two GEMMs: (8192 x 3072 x 512) and (8192 x 3072 x 1024).
//
// Round-5 changes vs round-4 (298 us; gemm 78.7, MfmaUtil 26%, BANK_CONFLICT 8.1M):
//  * Counted-vmcnt pipeline: raw s_barrier (no implicit vmcnt(0) drain!) x2 per
//    K-step + asm s_waitcnt vmcnt(3). stage(t+1) loads stay in flight across the
//    barriers + full compute of tile t (T4; __syncthreads was draining them).
//    Loads/thread uniform (3) via scratch equalizer so the count is wave-correct.
//  * k-major canonical layouts (e0T/WpT/inp1T = [k8][row] 16B chunks): staging
//    stays linear/coalesced for global_load_lds AND the LDS tile becomes k-major,
//    making every 8-lane group of ds_read_b128 contiguous 128 B -> conflict-free.
//  * XCD swizzle: bm-range per XCD (2MB A-set resident per 4MB L2), bn fastest.
//  * s_setprio(1) around MFMA cluster.
//
// ws layout (bytes), all 16B-aligned:
//   flag  @ 0
//   bc0   @ 1024        12,288  (3072 f32 combined bias, gate-interleaved)
//   bc1   @ 16384       12,288
//   Wp0   @ 32768       3,145,728   (k-major chunks [64][3072])
//   Wp1   @ 4194304     6,291,456   (k-major chunks [128][3072])
//   e0    @ 10485760    8,388,608   (k-major chunks [64][8192])
//   inp1  @ 18874368    16,777,216  (k-major chunks [128][8192])

using bf16x8 = __attribute__((ext_vector_type(8))) short;
using f32x4  = __attribute__((ext_vector_type(4))) float;

__device__ __forceinline__ unsigned short f2bf(float f)
{
    __hip_bfloat16 h = __float2bfloat16(f);
    return *(unsigned short*)&h;
}
__device__ __forceinline__ float sigf(float x)  { return 1.0f / (1.0f + __expf(-x)); }
__device__ __forceinline__ float tanhfast(float x)
{
    return 1.0f - 2.0f / (__expf(2.0f * x) + 1.0f);
}

__device__ __forceinline__ void gload16(const void* g, void* l)
{
    __builtin_amdgcn_global_load_lds(
        (const __attribute__((address_space(1))) unsigned int*)g,
        (__attribute__((address_space(3))) unsigned int*)l, 16, 0, 0);
}
// raw barrier, fenced so ds_reads/MFMA can't cross it at schedule time (rule #18)
#define SBAR() do { __builtin_amdgcn_sched_barrier(0); \
                    __builtin_amdgcn_s_barrier();      \
                    __builtin_amdgcn_sched_barrier(0); } while (0)

// ---- single prep dispatch: local dtype detect + gather + pack W + bias ----
// blocks: [0,2048) gather e0T | [2048,2816) pack Wp0 | [2816,4352) pack Wp1
//         [4352,4376) bias (12 bc0, 12 bc1); block 4352 publishes flag
__global__ __launch_bounds__(256)
void prep(const int* __restrict__ x, const void* __restrict__ emb,
          const void* __restrict__ Wih0, const void* __restrict__ Wih1,
          const void* __restrict__ bih0, const void* __restrict__ bhh0,
          const void* __restrict__ bih1, const void* __restrict__ bhh1,
          uint4* __restrict__ e0, uint4* __restrict__ Wp0, uint4* __restrict__ Wp1,
          float* __restrict__ bc0, float* __restrict__ bc1, int* __restrict__ flag)
{
    __shared__ int oks[4];
    {
        unsigned lo = ((const unsigned int*)emb)[threadIdx.x] & 0xFFFFu;
        int e = (lo >> 7) & 0xFF;
        int ok = ((e >= 96 && e < 160) || lo == 0) ? 1 : 0;
#pragma unroll
        for (int off = 32; off; off >>= 1) ok += __shfl_down(ok, off);
        if ((threadIdx.x & 63) == 0) oks[threadIdx.x >> 6] = ok;
    }
    __syncthreads();
    const bool isbf = (oks[0] + oks[1] + oks[2] + oks[3]) >= 192;
    const int bid = blockIdx.x, tid = threadIdx.x;

    if (bid < 2048) {                       // ---- gather e0T: chunk = k8*8192+m ----
        int idx = bid * 256 + tid;          // [0, 524288); dest chunk == idx
        int k8 = idx >> 13, m = idx & 8191;
        long srow = x[m];
        uint4 v;
        if (isbf) {
            v = ((const uint4*)emb)[srow * 64 + k8];
        } else {
            const float4* ef = (const float4*)emb;
            float4 a = ef[srow * 128 + k8 * 2], b = ef[srow * 128 + k8 * 2 + 1];
            unsigned short h[8] = { f2bf(a.x), f2bf(a.y), f2bf(a.z), f2bf(a.w),
                                    f2bf(b.x), f2bf(b.y), f2bf(b.z), f2bf(b.w) };
            v = *(uint4*)h;
        }
        e0[idx] = v;
    } else if (bid < 4352) {                // ---- pack WpT: chunk = k8*3072+n ----
        const bool L0 = bid < 2816;
        int idx = (L0 ? (bid - 2048) : (bid - 2816)) * 256 + tid;
        int k8 = idx / 3072, n = idx - k8 * 3072;
        int h = n / 6, gi = n - h * 6;      // gate-interleaved row n = h*6+gi
        int dir = (gi >= 3) ? 1 : 0;
        int gate = gi - dir * 3;            // 0:i 1:g 2:o
        int sg = (gate == 0) ? 0 : (gate + 1);
        long srcrow = dir * 2048 + sg * 512 + h;
        const void* src = L0 ? Wih0 : Wih1;
        uint4* dst = L0 ? Wp0 : Wp1;
        const int K4 = L0 ? 128 : 256, K8 = L0 ? 64 : 128;
        if (isbf) {
            dst[idx] = ((const uint4*)src)[srcrow * K8 + k8];
        } else {
            const float4* sf = (const float4*)src;
            float4 a = sf[srcrow * K4 + k8 * 2], b = sf[srcrow * K4 + k8 * 2 + 1];
            unsigned short h8[8] = { f2bf(a.x), f2bf(a.y), f2bf(a.z), f2bf(a.w),
                                     f2bf(b.x), f2bf(b.y), f2bf(b.z), f2bf(b.w) };
            dst[idx] = *(uint4*)h8;
        }
    } else {                                // ---- bias ----
        int b2 = bid - 4352;
        if (b2 == 0 && tid == 0) *flag = isbf ? 1 : 0;
        const bool L0 = b2 < 12;
        int n = (L0 ? b2 : (b2 - 12)) * 256 + tid;
        int h = n / 6, gi = n - h * 6;
        int dir = (gi >= 3) ? 1 : 0;
        int gate = gi - dir * 3;
        int sg = (gate == 0) ? 0 : (gate + 1);
        int s = dir * 2048 + sg * 512 + h;
        const void* bi = L0 ? bih0 : bih1;
        const void* bh = L0 ? bhh0 : bhh1;
        float* bc = L0 ? bc0 : bc1;
        float vi, vh;
        if (isbf) {
            vi = __bfloat162float(((const __hip_bfloat16*)bi)[s]);
            vh = __bfloat162float(((const __hip_bfloat16*)bh)[s]);
        } else {
            vi = ((const float*)bi)[s];
            vh = ((const float*)bh)[s];
        }
        bc[n] = vi + vh;
    }
}

// ---- fused GEMM + activation epilogue, counted-vmcnt double-buffer ----
// C(M x 3072) = A(M x K) * B(3072 x K)^T; A,B stored k-major as 16B chunks:
// A chunk = k8*8192 + m, B chunk = k8*3072 + n.
// Tile 256x96, BK=32, 512 thr = 8 waves (4 row x 2 col), wave 64x48 = 4x3 MFMA.
// LDS (k-major): A buf = [4 k8][256 row] chunks, B buf = [4 k8][96 n] chunks.
// Per K-step: stage(t+1) -> vmcnt(3) (stage(t) done, t+1 stays in flight) ->
// s_barrier -> ds_read+MFMA(t) -> s_barrier (reads done, next overwrite safe).
// ds_read_b128: 8-lane groups read 128 contiguous bytes -> conflict-free.
// d_out flat: h_last(2,32,512) @0 | c_last(2,32,512) @32768 | enc(B,T,2,H) @65536
template <int LAYER>
__global__ __launch_bounds__(512)
void gemm_fused(const unsigned short* __restrict__ A,
                const unsigned short* __restrict__ Bp,
                const float* __restrict__ bc,
                unsigned short* __restrict__ inp1,
                void* __restrict__ outv,
                const int* __restrict__ flag,
                int K)
{
    __shared__ __align__(16) char smem[45072];  // A dbuf 2x16K | B dbuf 2x6K | 16B scratch

    const int tid = threadIdx.x;
    // XCD swizzle: consecutive HW wg-ids round-robin XCDs; give each XCD a
    // contiguous bm-range (4 x 512KB A-set resident in its 4MB L2), bn fastest.
    const int raw = blockIdx.x + (blockIdx.y << 5);     // grid 32x32
    const int xcd = raw & 7, local = raw >> 3;
    const int bm = xcd * 4 + (local >> 5);
    const int bn = local & 31;

    const uint4* a4 = (const uint4*)A;
    const uint4* b4 = (const uint4*)Bp;

    // staging ownership (all chunk indices tid-linear => gload_lds-compatible):
    // A: LDS chunk c = k8l*256+row; thread owns c=tid (k8l=tid>>8,row=tid&255)
    //    and c=tid+512 (k8l+2, same row). B: c = k8l*96+n, threads 0..383.
    const int aRow = bm * 256 + (tid & 255);
    const int aK   = tid >> 8;                          // 0/1
    const int bK   = (tid < 384) ? (tid / 96) : 0;
    const int bN   = bn * 96 + ((tid < 384) ? (tid - (tid / 96) * 96) : 0);
    const bool bact = tid < 384;                        // wave-uniform (waves 0-5)

    const int wave = tid >> 6, lane = tid & 63;
    const int wr = (wave >> 1) * 64;                    // 0/64/128/192
    const int wc = (wave & 1) * 48;                     // 0/48
    const int lr = lane & 15, q = lane >> 4;

    f32x4 acc[4][3] = {};
    const int NT = K >> 5;

    auto stage = [&](int t) {
        const int buf = t & 1;
        const int k8b = t * 4;
        uint4* As4 = (uint4*)(smem + buf * 16384);
        uint4* Bs4 = (uint4*)(smem + 32768 + buf * 6144);
        const uint4* s0 = a4 + (long)(k8b + aK) * 8192 + aRow;
        gload16(s0, As4 + tid);
        gload16(s0 + 2L * 8192, As4 + tid + 512);
        if (bact) gload16(b4 + (long)(k8b + bK) * 3072 + bN, Bs4 + tid);
        else      gload16(s0, (uint4*)(smem + 45056));  // vmcnt equalizer (scratch)
    };

    stage(0);
    for (int t = 0; t < NT; ++t) {
        if (t + 1 < NT) {                               // uniform branch
            stage(t + 1);
            asm volatile("s_waitcnt vmcnt(3)" ::: "memory");   // stage(t) landed
        } else {
            asm volatile("s_waitcnt vmcnt(0)" ::: "memory");
        }
        SBAR();                                         // buf[t] visible to all waves

        const unsigned short* As = (const unsigned short*)(smem + (t & 1) * 16384);
        const unsigned short* Bs = (const unsigned short*)(smem + 32768 + (t & 1) * 6144);
        bf16x8 af[4], bf[3];
#pragma unroll
        for (int i = 0; i < 4; ++i)                     // chunk = q*256 + row
            af[i] = *(const bf16x8*)&As[(q * 256 + wr + i * 16 + lr) * 8];
#pragma unroll
        for (int j = 0; j < 3; ++j)                     // chunk = q*96 + n
            bf[j] = *(const bf16x8*)&Bs[(q * 96 + wc + j * 16 + lr) * 8];
        __builtin_amdgcn_s_setprio(1);
#pragma unroll
        for (int i = 0; i < 4; ++i)
#pragma unroll
            for (int j = 0; j < 3; ++j)
                acc[i][j] = __builtin_amdgcn_mfma_f32_16x16x32_bf16(af[i], bf[j], acc[i][j], 0, 0, 0);
        __builtin_amdgcn_s_setprio(0);
        SBAR();                                         // all reads of buf[t] done
    }

    // ---- fused epilogue: Cs[64][97] overlays A buffers (K-loop ended on SBAR) ----
    float* Cs = (float*)smem;
    const bool isbf = (*flag != 0);
    auto store = [&](long i, float v) {
        if (isbf) ((__hip_bfloat16*)outv)[i] = __float2bfloat16(v);
        else      ((float*)outv)[i] = v;
    };

    const int hl = tid & 15;
    float bcv[6];
#pragma unroll
    for (int gi = 0; gi < 6; ++gi) bcv[gi] = bc[bn * 96 + hl * 6 + gi];

    for (int p = 0; p < 4; ++p) {                       // 64 rows per pass
        if ((wave >> 1) == p) {
            // D layout: col = lane&15, row = (lane>>4)*4 + reg (m89/m91-verified)
#pragma unroll
            for (int i = 0; i < 4; ++i)
#pragma unroll
                for (int j = 0; j < 3; ++j)
#pragma unroll
                    for (int r = 0; r < 4; ++r)
                        Cs[(i * 16 + q * 4 + r) * 97 + wc + j * 16 + lr] = acc[i][j][r];
        }
        __syncthreads();
#pragma unroll
        for (int t2 = 0; t2 < 2; ++t2) {
            int ml = (tid >> 4) + t2 * 32;              // 0..63 local row
            float z[6];
#pragma unroll
            for (int gi = 0; gi < 6; ++gi) z[gi] = Cs[ml * 97 + hl * 6 + gi] + bcv[gi];
            float c0 = sigf(z[0]) * tanhfast(z[1]);     // forward dir
            float h0 = sigf(z[2]) * tanhfast(c0);
            float c1 = sigf(z[3]) * tanhfast(z[4]);     // backward dir
            float h1 = sigf(z[5]) * tanhfast(c1);

            long m = (long)bm * 256 + p * 64 + ml;
            int hg = bn * 16 + hl;

            if constexpr (LAYER == 0) {                 // inp1T: chunk=(col>>3)*8192+m
                int c0i = hg, c1i = 512 + hg;
                inp1[((long)(c0i >> 3) * 8192 + m) * 8 + (c0i & 7)] = f2bf(h0);
                inp1[((long)(c1i >> 3) * 8192 + m) * 8 + (c1i & 7)] = f2bf(h1);
            }
            store(65536 + m * 1024 + LAYER * 512 + hg, h0 + h1);    // encoder_out
            if ((m & 255) == 255) {                     // t == T-1
                int b = (int)(m >> 8);
                store(LAYER * 16384 + b * 512 + hg, h0);            // h_last (fwd)
                store(32768 + LAYER * 16384 + b * 512 + hg, c0);    // c_last (fwd)
            }
        }
        if (p < 3) __syncthreads();
    }
}

extern "C" void kernel_launch(void* const* d_in, const int* in_sizes, int n_in,
                              void* d_out, int out_size, void* d_ws, size_t ws_size,
                              hipStream_t stream)
{
    const int* x      = (const int*)d_in[0];
    const void* emb   = d_in[1];
    const void* Wih0  = d_in[2];
    const void* bih0  = d_in[4];
    const void* bhh0  = d_in[5];
    const void* Wih1  = d_in[6];
    const void* bih1  = d_in[8];
    const void* bhh1  = d_in[9];

    char* ws = (char*)d_ws;
    int*   flag           = (int*)(ws);
    float* bc0            = (float*)(ws + 1024);
    float* bc1            = (float*)(ws + 16384);
    unsigned short* Wp0   = (unsigned short*)(ws + 32768);
    unsigned short* Wp1   = (unsigned short*)(ws + 4194304);
    unsigned short* e0    = (unsigned short*)(ws + 10485760);
    unsigned short* inp1  = (unsigned short*)(ws + 18874368);

    prep<<<4376, 256, 0, stream>>>(x, emb, Wih0, Wih1, bih0, bhh0, bih1, bhh1,
                                   (uint4*)e0, (uint4*)Wp0, (uint4*)Wp1, bc0, bc1, flag);

    gemm_fused<0><<<dim3(32, 32), 512, 0, stream>>>(e0, Wp0, bc0, inp1, d_out, flag, 512);
    gemm_fused<1><<<dim3(32, 32), 512, 0, stream>>>(inp1, Wp1, bc1, nullptr, d_out, flag, 1024);
}

// Round 4
// 287.592 us; speedup vs baseline: 1.1714x; 1.0260x over previous
//
#include <hip/hip_runtime.h>
#include <hip/hip_bf16.h>

// Encoder_multi: zero-state single-step bidirectional 2-layer LSTM.
// h0=c0=0 => no recurrence, W_hh unused, forget gate dead.
//   gates = inp @ W_ih^T + (b_ih+b_hh); c = sig(i)*tanh(g); h = sig(o)*tanh(c)
// Two GEMMs: (8192 x 3072 x 512) and (8192 x 3072 x 1024).
//
// Round-6 changes vs round-5 (295 us; gemm1 67.3, MfmaUtil 32.7%, conflicts 786K):
//  * Triple-buffer depth-2 pipeline: stage(t+2) each iter, s_waitcnt vmcnt(6)
//    -> 2 stages (6 loads) stay in flight across the whole compute phase;
//    depth-1 (vmcnt(3)) was still latency-exposed since most stage loads are
//    L2 misses (~500+ cy > one compute phase). LDS 66KB, 2 blocks/CU.
//  * K is a template parameter; K-loop fully unrolled -> t%3 buffer index and
//    all addresses compile-time (kills in-loop address VALU; VALUBusy 45%).
//  * vmcnt equalizer: waves 6-7 duplicate waves 4-5's B loads (same src+dst,
//    benign) -> uniform 3 loads/thread; removes the old out-of-bounds scratch.
//  * prep rewritten with LDS-transpose tiles (32 rows x 64 chunks): coalesced
//    row-major reads AND coalesced k-major writes (round-5 read side was
//    scattered 16B -> ~+14us regression).
//
// ws layout (bytes), all 16B-aligned:
//   flag  @ 0
//   bc0   @ 1024        12,288  (3072 f32 combined bias, gate-interleaved)
//   bc1   @ 16384       12,288
//   Wp0   @ 32768       3,145,728   (k-major chunks [64][3072])
//   Wp1   @ 4194304     6,291,456   (k-major chunks [128][3072])
//   e0    @ 10485760    8,388,608   (k-major chunks [64][8192])
//   inp1  @ 18874368    16,777,216  (k-major chunks [128][8192])

using bf16x8 = __attribute__((ext_vector_type(8))) short;
using f32x4  = __attribute__((ext_vector_type(4))) float;

__device__ __forceinline__ unsigned short f2bf(float f)
{
    __hip_bfloat16 h = __float2bfloat16(f);
    return *(unsigned short*)&h;
}
__device__ __forceinline__ float sigf(float x)  { return 1.0f / (1.0f + __expf(-x)); }
__device__ __forceinline__ float tanhfast(float x)
{
    return 1.0f - 2.0f / (__expf(2.0f * x) + 1.0f);
}

__device__ __forceinline__ void gload16(const void* g, void* l)
{
    __builtin_amdgcn_global_load_lds(
        (const __attribute__((address_space(1))) unsigned int*)g,
        (__attribute__((address_space(3))) unsigned int*)l, 16, 0, 0);
}
// raw barrier, fenced so ds_reads/MFMA can't cross it at schedule time (rule #18)
#define SBAR() do { __builtin_amdgcn_sched_barrier(0); \
                    __builtin_amdgcn_s_barrier();      \
                    __builtin_amdgcn_sched_barrier(0); } while (0)

// ---- single prep dispatch: detect + transpose-gather + transpose-pack + bias ----
// blocks: [0,256) e0T (32 m x 64 k8 tiles) | [256,352) Wp0 (32 n x 64 k8)
//         [352,544) Wp1 (32 n x 64 k8, 2 k8-halves) | [544,568) bias; 544 -> flag
__global__ __launch_bounds__(256)
void prep(const int* __restrict__ x, const void* __restrict__ emb,
          const void* __restrict__ Wih0, const void* __restrict__ Wih1,
          const void* __restrict__ bih0, const void* __restrict__ bhh0,
          const void* __restrict__ bih1, const void* __restrict__ bhh1,
          uint4* __restrict__ e0, uint4* __restrict__ Wp0, uint4* __restrict__ Wp1,
          float* __restrict__ bc0, float* __restrict__ bc1, int* __restrict__ flag)
{
    __shared__ int oks[4];
    __shared__ uint4 panel[32][65];             // +1 chunk pad: 4-way on T-read
    {
        unsigned lo = ((const unsigned int*)emb)[threadIdx.x] & 0xFFFFu;
        int e = (lo >> 7) & 0xFF;
        int ok = ((e >= 96 && e < 160) || lo == 0) ? 1 : 0;
#pragma unroll
        for (int off = 32; off; off >>= 1) ok += __shfl_down(ok, off);
        if ((threadIdx.x & 63) == 0) oks[threadIdx.x >> 6] = ok;
    }
    __syncthreads();
    const bool isbf = (oks[0] + oks[1] + oks[2] + oks[3]) >= 192;
    const int bid = blockIdx.x, tid = threadIdx.x;

    if (bid < 256) {                            // ---- e0T: rows read coalesced ----
        const int mbase = bid * 32;
#pragma unroll
        for (int j = 0; j < 8; ++j) {
            int li = j * 256 + tid;
            int ml = li >> 6, k8 = li & 63;     // 64 lanes: same row, consec k8
            long srow = x[mbase + ml];
            uint4 v;
            if (isbf) {
                v = ((const uint4*)emb)[srow * 64 + k8];
            } else {
                const float4* ef = (const float4*)emb;
                float4 a = ef[srow * 128 + k8 * 2], b = ef[srow * 128 + k8 * 2 + 1];
                unsigned short h[8] = { f2bf(a.x), f2bf(a.y), f2bf(a.z), f2bf(a.w),
                                        f2bf(b.x), f2bf(b.y), f2bf(b.z), f2bf(b.w) };
                v = *(uint4*)h;
            }
            panel[ml][k8] = v;
        }
        __syncthreads();
#pragma unroll
        for (int j = 0; j < 8; ++j) {           // k-major write, 512B contiguous
            int li = j * 256 + tid;
            int k8 = li >> 5, ml = li & 31;
            e0[(long)k8 * 8192 + mbase + ml] = panel[ml][k8];
        }
    } else if (bid < 544) {                     // ---- pack WpT ----
        const bool L0 = bid < 352;
        const int t = L0 ? (bid - 256) : (bid - 352);
        const int nbase  = (L0 ? t : (t >> 1)) * 32;
        const int k8base = L0 ? 0 : (t & 1) * 64;
        const void* src = L0 ? Wih0 : Wih1;
        uint4* dst = L0 ? Wp0 : Wp1;
        const int K8s = L0 ? 64 : 128;
#pragma unroll
        for (int j = 0; j < 8; ++j) {
            int li = j * 256 + tid;
            int nl = li >> 6, k8l = li & 63;    // 64 lanes: same src row, consec k8
            int n = nbase + nl;                 // gate-interleaved row n = h*6+gi
            int h = n / 6, gi = n - h * 6;
            int dir = (gi >= 3) ? 1 : 0;
            int gate = gi - dir * 3;            // 0:i 1:g 2:o
            int sg = (gate == 0) ? 0 : (gate + 1);
            long srcrow = dir * 2048 + sg * 512 + h;
            uint4 v;
            if (isbf) {
                v = ((const uint4*)src)[srcrow * K8s + k8base + k8l];
            } else {
                const float4* sf = (const float4*)src;
                long c2 = (srcrow * K8s + k8base + k8l) * 2;
                float4 a = sf[c2], b = sf[c2 + 1];
                unsigned short h8[8] = { f2bf(a.x), f2bf(a.y), f2bf(a.z), f2bf(a.w),
                                         f2bf(b.x), f2bf(b.y), f2bf(b.z), f2bf(b.w) };
                v = *(uint4*)h8;
            }
            panel[nl][k8l] = v;
        }
        __syncthreads();
#pragma unroll
        for (int j = 0; j < 8; ++j) {
            int li = j * 256 + tid;
            int k8l = li >> 5, nl = li & 31;
            dst[(long)(k8base + k8l) * 3072 + nbase + nl] = panel[nl][k8l];
        }
    } else {                                    // ---- bias ----
        int b2 = bid - 544;
        if (b2 == 0 && tid == 0) *flag = isbf ? 1 : 0;
        const bool L0 = b2 < 12;
        int n = (L0 ? b2 : (b2 - 12)) * 256 + tid;
        int h = n / 6, gi = n - h * 6;
        int dir = (gi >= 3) ? 1 : 0;
        int gate = gi - dir * 3;
        int sg = (gate == 0) ? 0 : (gate + 1);
        int s = dir * 2048 + sg * 512 + h;
        const void* bi = L0 ? bih0 : bih1;
        const void* bh = L0 ? bhh0 : bhh1;
        float* bc = L0 ? bc0 : bc1;
        float vi, vh;
        if (isbf) {
            vi = __bfloat162float(((const __hip_bfloat16*)bi)[s]);
            vh = __bfloat162float(((const __hip_bfloat16*)bh)[s]);
        } else {
            vi = ((const float*)bi)[s];
            vh = ((const float*)bh)[s];
        }
        bc[n] = vi + vh;
    }
}

// ---- fused GEMM + activation epilogue, triple-buffer depth-2 counted vmcnt ----
// C(M x 3072) = A(M x K) * B(3072 x K)^T; A,B k-major 16B chunks:
// A chunk = k8*8192 + m, B chunk = k8*3072 + n.
// Tile 256x96, BK=32, 512 thr = 8 waves (4 row x 2 col), wave 64x48 = 4x3 MFMA.
// LDS: A 3x16K @0 | B 3x6K @49152 = 66KB (2 blocks/CU).
// Steady state: stages t+1, t+2 in flight (6 loads/thread) across compute(t);
// vmcnt(6) guarantees stage(t) landed. Fully unrolled (K constexpr) -> t%3 and
// all addressing compile-time. Waves 6-7 duplicate waves 4-5's B loads so every
// thread issues exactly 3 loads/stage (vmcnt arithmetic wave-correct).
// d_out flat: h_last(2,32,512) @0 | c_last(2,32,512) @32768 | enc(B,T,2,H) @65536
template <int LAYER, int K>
__global__ __launch_bounds__(512)
void gemm_fused(const unsigned short* __restrict__ A,
                const unsigned short* __restrict__ Bp,
                const float* __restrict__ bc,
                unsigned short* __restrict__ inp1,
                void* __restrict__ outv,
                const int* __restrict__ flag)
{
    constexpr int NT = K / 32;
    __shared__ __align__(16) char smem[67584];

    const int tid = threadIdx.x;
    // XCD swizzle: contiguous bm-range per XCD, bn fastest.
    const int raw = blockIdx.x + (blockIdx.y << 5);     // grid 32x32
    const int xcd = raw & 7, local = raw >> 3;
    const int bm = xcd * 4 + (local >> 5);
    const int bn = local & 31;

    const uint4* a4 = (const uint4*)A;
    const uint4* b4 = (const uint4*)Bp;

    // A: LDS chunk c = k8l*256+row; thread owns c=tid and c=tid+512.
    // B: LDS chunk c = k8l*96+n = btid; waves 6-7 mirror waves 4-5.
    const int btid = (tid < 384) ? tid : (tid - 128);
    const long aOff = (long)(tid >> 8) * 8192 + bm * 256 + (tid & 255);
    const long bOff = (long)(btid / 96) * 3072 + bn * 96 + (btid % 96);

    const int wave = tid >> 6, lane = tid & 63;
    const int wr = (wave >> 1) * 64;                    // 0/64/128/192
    const int wc = (wave & 1) * 48;                     // 0/48
    const int lr = lane & 15, q = lane >> 4;

    f32x4 acc[4][3] = {};

    auto stage = [&](int s) {
        const int buf = s % 3;
        uint4* As4 = (uint4*)(smem + buf * 16384);
        uint4* Bs4 = (uint4*)(smem + 49152 + buf * 6144);
        const uint4* ap = a4 + (long)s * 32768 + aOff;  // 4 k8-slices per stage
        gload16(ap, As4 + tid);
        gload16(ap + 16384, As4 + tid + 512);
        gload16(b4 + (long)s * 12288 + bOff, Bs4 + btid);
    };

    stage(0);
    stage(1);
#pragma unroll
    for (int t = 0; t < NT; ++t) {
        if (t + 2 < NT) {
            stage(t + 2);
            asm volatile("s_waitcnt vmcnt(6)" ::: "memory");    // stage(t) landed
        } else if (t + 1 < NT) {
            asm volatile("s_waitcnt vmcnt(3)" ::: "memory");
        } else {
            asm volatile("s_waitcnt vmcnt(0)" ::: "memory");
        }
        SBAR();                                         // buf[t] visible to all waves

        const unsigned short* As = (const unsigned short*)(smem + (t % 3) * 16384);
        const unsigned short* Bs = (const unsigned short*)(smem + 49152 + (t % 3) * 6144);
        bf16x8 af[4], bf[3];
#pragma unroll
        for (int i = 0; i < 4; ++i)                     // chunk = q*256 + row
            af[i] = *(const bf16x8*)&As[(q * 256 + wr + i * 16 + lr) * 8];
#pragma unroll
        for (int j = 0; j < 3; ++j)                     // chunk = q*96 + n
            bf[j] = *(const bf16x8*)&Bs[(q * 96 + wc + j * 16 + lr) * 8];
        __builtin_amdgcn_s_setprio(1);
#pragma unroll
        for (int i = 0; i < 4; ++i)
#pragma unroll
            for (int j = 0; j < 3; ++j)
                acc[i][j] = __builtin_amdgcn_mfma_f32_16x16x32_bf16(af[i], bf[j], acc[i][j], 0, 0, 0);
        __builtin_amdgcn_s_setprio(0);
        SBAR();                                         // all reads of buf[t] done
    }

    // ---- fused epilogue: Cs[64][97] overlays A buffers ----
    float* Cs = (float*)smem;
    const bool isbf = (*flag != 0);
    auto store = [&](long i, float v) {
        if (isbf) ((__hip_bfloat16*)outv)[i] = __float2bfloat16(v);
        else      ((float*)outv)[i] = v;
    };

    const int hl = tid & 15;
    float bcv[6];
#pragma unroll
    for (int gi = 0; gi < 6; ++gi) bcv[gi] = bc[bn * 96 + hl * 6 + gi];

    for (int p = 0; p < 4; ++p) {                       // 64 rows per pass
        if ((wave >> 1) == p) {
            // D layout: col = lane&15, row = (lane>>4)*4 + reg (m89/m91-verified)
#pragma unroll
            for (int i = 0; i < 4; ++i)
#pragma unroll
                for (int j = 0; j < 3; ++j)
#pragma unroll
                    for (int r = 0; r < 4; ++r)
                        Cs[(i * 16 + q * 4 + r) * 97 + wc + j * 16 + lr] = acc[i][j][r];
        }
        __syncthreads();
#pragma unroll
        for (int t2 = 0; t2 < 2; ++t2) {
            int ml = (tid >> 4) + t2 * 32;              // 0..63 local row
            float z[6];
#pragma unroll
            for (int gi = 0; gi < 6; ++gi) z[gi] = Cs[ml * 97 + hl * 6 + gi] + bcv[gi];
            float c0 = sigf(z[0]) * tanhfast(z[1]);     // forward dir
            float h0 = sigf(z[2]) * tanhfast(c0);
            float c1 = sigf(z[3]) * tanhfast(z[4]);     // backward dir
            float h1 = sigf(z[5]) * tanhfast(c1);

            long m = (long)bm * 256 + p * 64 + ml;
            int hg = bn * 16 + hl;

            if constexpr (LAYER == 0) {                 // inp1T: chunk=(col>>3)*8192+m
                int c0i = hg, c1i = 512 + hg;
                inp1[((long)(c0i >> 3) * 8192 + m) * 8 + (c0i & 7)] = f2bf(h0);
                inp1[((long)(c1i >> 3) * 8192 + m) * 8 + (c1i & 7)] = f2bf(h1);
            }
            store(65536 + m * 1024 + LAYER * 512 + hg, h0 + h1);    // encoder_out
            if ((m & 255) == 255) {                     // t == T-1
                int b = (int)(m >> 8);
                store(LAYER * 16384 + b * 512 + hg, h0);            // h_last (fwd)
                store(32768 + LAYER * 16384 + b * 512 + hg, c0);    // c_last (fwd)
            }
        }
        if (p < 3) __syncthreads();
    }
}

extern "C" void kernel_launch(void* const* d_in, const int* in_sizes, int n_in,
                              void* d_out, int out_size, void* d_ws, size_t ws_size,
                              hipStream_t stream)
{
    const int* x      = (const int*)d_in[0];
    const void* emb   = d_in[1];
    const void* Wih0  = d_in[2];
    const void* bih0  = d_in[4];
    const void* bhh0  = d_in[5];
    const void* Wih1  = d_in[6];
    const void* bih1  = d_in[8];
    const void* bhh1  = d_in[9];

    char* ws = (char*)d_ws;
    int*   flag           = (int*)(ws);
    float* bc0            = (float*)(ws + 1024);
    float* bc1            = (float*)(ws + 16384);
    unsigned short* Wp0   = (unsigned short*)(ws + 32768);
    unsigned short* Wp1   = (unsigned short*)(ws + 4194304);
    unsigned short* e0    = (unsigned short*)(ws + 10485760);
    unsigned short* inp1  = (unsigned short*)(ws + 18874368);

    prep<<<568, 256, 0, stream>>>(x, emb, Wih0, Wih1, bih0, bhh0, bih1, bhh1,
                                  (uint4*)e0, (uint4*)Wp0, (uint4*)Wp1, bc0, bc1, flag);

    gemm_fused<0, 512><<<dim3(32, 32), 512, 0, stream>>>(e0, Wp0, bc0, inp1, d_out, flag);
    gemm_fused<1, 1024><<<dim3(32, 32), 512, 0, stream>>>(inp1, Wp1, bc1, nullptr, d_out, flag);
}